// Round 10
// baseline (219.931 us; speedup 1.0000x reference)
//
#include <hip/hip_runtime.h>
#include <hip/hip_cooperative_groups.h>
#include <stdint.h>

namespace cg = cooperative_groups;

// Problem constants
#define BATCH 16
#define MGT 256
#define NPROP 8192
#define NUM_CLASSES 80
#define IGNORED_CLASS 80
#define NUM_FG 128
#define NUM_BG 384
#define SENT 0xFFFFFFFFu
#define BS 1024
#define PPB 512                               // proposals per block (split-M x2)
#define NUM_BLOCKS (BATCH * (NPROP / PPB))    // 256
#define NUM_SAMPLE_JOBS (BATCH * 2)           // 32 (row, pass)
#define KPT 8                                 // sample keys per thread

typedef unsigned long long u64;

// d_out FLOAT32 layout (confirmed): matched_vals[16,8192] | matched_idxs[16,8192]
//   | sampled_idxs[16,512] | sampled_classes[16,512] | sampled_gt[16,512]
// ws: packed[B*N] int32 (512 KiB).  packed = (midx<<16) | (cls+1).

struct SampleSmem {
    uint32_t hist[4096];     // 16 KB
    uint32_t wsums[16];
    uint32_t sc[8];          // b1,p1,b2,p2,b3,p3,C,selcount
    u64      sel[NUM_BG];    // 3 KB
};
struct MatchSmem { u64 skey[PPB]; };          // 4 KB
union Smem { SampleSmem s; MatchSmem m; };

// ---------------- scan helpers (1024 threads = 16 waves; R9-verified) -------
__device__ __forceinline__ uint32_t wave_incl_scan_u32(uint32_t x) {
#pragma unroll
    for (int d = 1; d < 64; d <<= 1) {
        uint32_t y = __shfl_up(x, d, 64);
        if ((threadIdx.x & 63) >= d) x += y;
    }
    return x;
}

__device__ uint32_t block_excl_scan(uint32_t s, uint32_t* wsums) {
    const int tid = threadIdx.x, lane = tid & 63, wid = tid >> 6;
    __syncthreads();                 // protect wsums reuse across calls
    uint32_t incl = wave_incl_scan_u32(s);
    if (lane == 63) wsums[wid] = incl;
    __syncthreads();
    if (wid == 0) {
        uint32_t w  = (lane < 16) ? wsums[lane] : 0u;
        uint32_t wi = wave_incl_scan_u32(w);
        if (lane < 16) wsums[lane] = wi - w;
    }
    __syncthreads();
    return wsums[wid] + (incl - s);
}

// inclusive-scan hist[4096] in place; find bin with incl >= kk > prev.
__device__ void scan_and_find(uint32_t* hist, uint32_t* wsums, uint32_t kk,
                              uint32_t* sc_b, uint32_t* sc_p) {
    const int tid = threadIdx.x;
    __syncthreads();                 // histogram atomics complete
    const int base = tid * 4;
    uint32_t v0 = hist[base], v1 = hist[base+1], v2 = hist[base+2], v3 = hist[base+3];
    uint32_t pre = block_excl_scan(v0+v1+v2+v3, wsums);
    uint32_t i0 = pre+v0, i1 = i0+v1, i2 = i1+v2, i3 = i2+v3;
    hist[base] = i0; hist[base+1] = i1; hist[base+2] = i2; hist[base+3] = i3;
    __syncthreads();
    uint32_t prev = (base == 0) ? 0u : hist[base-1];
    uint32_t inc[4] = {i0, i1, i2, i3};
#pragma unroll
    for (int j = 0; j < 4; ++j) {
        if (inc[j] >= kk && prev < kk) { *sc_b = (uint32_t)(base+j); *sc_p = prev; }
        prev = inc[j];
    }
    __syncthreads();
}

// ---------------- sample: radix-select top-k (R9-verified semantics) --------
// pm[j] = ~ord(pri[cbase+j]) preloaded in registers (smaller = higher priority).
__device__ void sample_pass(SampleSmem* S, int b, int pass, const uint32_t* pm,
                            const int* __restrict__ packed,
                            float* __restrict__ out)
{
    const int tid = threadIdx.x;
    const int K   = pass ? NUM_BG : NUM_FG;
    const int off = pass ? NUM_FG : 0;

    const int* pk = packed + (size_t)b * NPROP;

    float* s_idx = out + (size_t)2 * BATCH * NPROP + (size_t)b * 512;
    float* s_cls = s_idx + (size_t)BATCH * 512;
    float* s_gt  = s_idx + (size_t)2 * BATCH * 512;

    if (tid < 8) S->sc[tid] = 0u;
    for (int i = tid; i < 4096; i += BS) S->hist[i] = 0u;
    __syncthreads();

    // keys; cbase = tid*8 -> ascending-index contiguous ownership
    uint32_t key[KPT];
    const int cbase = tid * KPT;
    uint32_t creal = 0;
#pragma unroll
    for (int j = 0; j < KPT; ++j) {
        const int c = (pk[cbase + j] & 0xFFFF) - 1;
        const bool m = pass ? (c == NUM_CLASSES) : (c >= 0 && c != NUM_CLASSES);
        key[j] = m ? pm[j] : SENT;               // real keys < 0x80000000
        u64 bal = __ballot(m);
        if ((tid & 63) == 0) creal += __popcll(bal);
    }
    if ((tid & 63) == 0 && creal) atomicAdd(&S->sc[6], creal);
    __syncthreads();
    const uint32_t C    = S->sc[6];
    const uint32_t ksel = (C < (uint32_t)K) ? C : (uint32_t)K;

    if (C > 0) {
        uint32_t Hstar, k4;
        if (C <= (uint32_t)K) {
            // shortcut: every real candidate is selected; no radix needed
            Hstar = 0x80000000u;  k4 = 0u;       // take = (key < Hstar)
        } else {
            // L1: bits [31:20]
#pragma unroll
            for (int j = 0; j < KPT; ++j)
                if (key[j] < 0x80000000u) atomicAdd(&S->hist[key[j] >> 20], 1u);
            scan_and_find(S->hist, S->wsums, ksel, &S->sc[0], &S->sc[1]);
            const uint32_t b1 = S->sc[0], p1 = S->sc[1];
            const uint32_t k2 = ksel - p1;
            for (int i = tid; i < 4096; i += BS) S->hist[i] = 0u;
            __syncthreads();

            // L2: bits [19:8] within b1
#pragma unroll
            for (int j = 0; j < KPT; ++j)
                if ((key[j] >> 20) == b1) atomicAdd(&S->hist[(key[j] >> 8) & 0xFFFu], 1u);
            scan_and_find(S->hist, S->wsums, k2, &S->sc[2], &S->sc[3]);
            const uint32_t b2 = S->sc[2], p2 = S->sc[3];
            const uint32_t k3 = k2 - p2;
            for (int i = tid; i < 4096; i += BS) S->hist[i] = 0u;
            __syncthreads();

            // L3: bits [7:0] within (b1,b2) -> exact k-th key H*
            const uint32_t top24 = (b1 << 12) | b2;
#pragma unroll
            for (int j = 0; j < KPT; ++j)
                if ((key[j] >> 8) == top24) atomicAdd(&S->hist[key[j] & 0xFFu], 1u);
            scan_and_find(S->hist, S->wsums, k3, &S->sc[4], &S->sc[5]);
            Hstar = (b1 << 20) | (b2 << 8) | S->sc[4];
            k4    = k3 - S->sc[5];               // ties at H*, taken idx-ascending
        }

        // tie prefix (idx-ordered) + compaction into sel[]
        uint32_t ssum = 0;
#pragma unroll
        for (int j = 0; j < KPT; ++j) ssum += (key[j] == Hstar);
        uint32_t run = block_excl_scan(ssum, S->wsums);
#pragma unroll
        for (int j = 0; j < KPT; ++j) {
            bool take = false;
            if (key[j] < Hstar) take = true;
            else if (key[j] == Hstar) { take = (run < k4); ++run; }
            if (take) {
                uint32_t pos = atomicAdd(&S->sc[7], 1u);
                S->sel[pos] = ((u64)key[j] << 32) | (uint32_t)(cbase + j);
            }
        }
        __syncthreads();
        const uint32_t Scnt = S->sc[7];          // == ksel

        // rank scatter: rank = #(keys < mine); keys unique (idx in low bits)
        for (uint32_t j = tid; j < Scnt; j += BS) {
            const u64 kj = S->sel[j];
            uint32_t r = 0;
            for (uint32_t i = 0; i < Scnt; ++i) r += (S->sel[i] < kj);
            const uint32_t idx = (uint32_t)kj;
            const int pv = pk[idx];
            s_idx[off + r] = (float)idx;
            s_cls[off + r] = (float)((pv & 0xFFFF) - 1);
            s_gt[off + r]  = (float)(pv >> 16);
        }
    }

    // filler: first (K - ksel) masked-out indices ascending (invalid slots)
    if (ksel < (uint32_t)K) {
        const uint32_t F = (uint32_t)K - ksel;
        uint32_t sv = 0;
#pragma unroll
        for (int j = 0; j < KPT; ++j) sv += (key[j] == SENT);
        uint32_t run = block_excl_scan(sv, S->wsums);
#pragma unroll
        for (int j = 0; j < KPT; ++j) {
            if (key[j] == SENT) {
                if (run < F) {
                    const int slot = off + (int)ksel + (int)run;
                    s_idx[slot] = (float)(cbase + j);
                    s_cls[slot] = -1.0f;
                    s_gt[slot]  = -1.0f;
                }
                ++run;
            }
        }
    }
}

// Cooperative: 256 blocks x 1024 threads. Match (split-M x2), grid.sync(),
// then blocks 0..31 each run one (row, pass) radix-select in parallel.
__global__ __launch_bounds__(BS) void fused_kernel(
    const float* __restrict__ gt_boxes, const int* __restrict__ gt_classes,
    const float* __restrict__ prop_boxes, const float* __restrict__ pri,
    float* __restrict__ out, int* __restrict__ packed)
{
#pragma clang fp contract(off)
    __shared__ Smem sm;

    const int tid  = threadIdx.x;
    const int b    = blockIdx.x >> 4;            // 16 chunks/row
    const int n    = ((blockIdx.x & 15) << 9) | (tid & (PPB - 1));
    const int half = tid >> 9;                   // wave-uniform

    // ---- match phase (R9-verified math; area recomputed inline) ----
    const float4* gt4 = (const float4*)gt_boxes + (size_t)b * MGT;
    const float4 p = ((const float4*)prop_boxes)[(size_t)b * NPROP + n];
    const float ap = (p.z - p.x) * (p.w - p.y);

    float best = 0.0f;
    int   bidx = 0;
    const int m0 = half * 128;
#pragma unroll 4
    for (int mm = 0; mm < 128; ++mm) {
        const int m = m0 + mm;
        const float4 g = gt4[m];                 // wave-uniform -> s_load
        float ag  = (g.z - g.x) * (g.w - g.y);   // np op order, no FMA
        float ltx = fmaxf(g.x, p.x);
        float lty = fmaxf(g.y, p.y);
        float rbx = fminf(g.z, p.z);
        float rby = fminf(g.w, p.w);
        float w = fmaxf(rbx - ltx, 0.0f);
        float h = fmaxf(rby - lty, 0.0f);
        float inter = w * h;
        float s   = ag + ap;                     // area_g + area_p
        float uni = s - inter;
        // conservative filter (R8/R9-verified): no true candidate skipped
        float thr = (best * uni) * 0.9999996f;
        if (inter > thr) {
            float iou = (uni > 0.0f) ? (inter / uni) : 0.0f;
            if (iou > best) { best = iou; bidx = m; }   // strict > = first idx
        }
    }
    // combine halves: max u64 key = larger iou, tie -> smaller gt idx
    u64 key = ((u64)__float_as_uint(best) << 32) | (uint32_t)(255 - bidx);
    const int pl = tid & (PPB - 1);
    if (half) sm.m.skey[pl] = key;
    __syncthreads();
    if (half == 0) {
        u64 o = sm.m.skey[pl];
        if (o > key) key = o;
        float bestf = __uint_as_float((uint32_t)(key >> 32));
        int   bi    = 255 - (int)(key & 0xFFu);

        const bool matched = (bestf >= 0.5f);
        int c = gt_classes[b * MGT + bi];
        if (c == IGNORED_CLASS) c = -1;
        if (!matched) c = NUM_CLASSES;

        const size_t on = (size_t)b * NPROP + n;
        out[on]                         = bestf;
        out[(size_t)BATCH * NPROP + on] = (float)bi;
        packed[on] = (bi << 16) | (c + 1);
    }

    // ---- sampler blocks preload their row's priorities (input-only) ----
    uint32_t pm[KPT] = {0};
    const int srow = blockIdx.x >> 1;
    if (blockIdx.x < NUM_SAMPLE_JOBS) {
        const float* pr = pri + (size_t)srow * NPROP;
#pragma unroll
        for (int j = 0; j < KPT; ++j) {
            uint32_t bits = __float_as_uint(pr[tid * KPT + j]);
            uint32_t ord  = (bits & 0x80000000u) ? ~bits : (bits | 0x80000000u);
            pm[j] = ~ord;                        // smaller == higher priority
        }
    }

    __threadfence();                             // publish packed[] grid-wide
    cg::this_grid().sync();                      // cooperative grid barrier

    if (blockIdx.x >= NUM_SAMPLE_JOBS) return;
    __threadfence();                             // acquire
    sample_pass(&sm.s, srow, blockIdx.x & 1, pm, packed, out);
}

extern "C" void kernel_launch(void* const* d_in, const int* in_sizes, int n_in,
                              void* d_out, int out_size, void* d_ws, size_t ws_size,
                              hipStream_t stream) {
    const float* gt_boxes   = (const float*)d_in[0];
    const int*   gt_classes = (const int*)d_in[1];
    const float* prop_boxes = (const float*)d_in[2];
    const float* rand_pri   = (const float*)d_in[3];
    float* out  = (float*)d_out;
    int* packed = (int*)d_ws;                    // [B*N] = 512 KiB

    void* kargs[] = { (void*)&gt_boxes, (void*)&gt_classes, (void*)&prop_boxes,
                      (void*)&rand_pri, (void*)&out, (void*)&packed };
    hipLaunchCooperativeKernel((void*)fused_kernel, dim3(NUM_BLOCKS), dim3(BS),
                               kargs, 0, stream);
}

// Round 11
// 105.418 us; speedup vs baseline: 2.0863x; 2.0863x over previous
//
#include <hip/hip_runtime.h>
#include <stdint.h>

// Problem constants
#define BATCH 16
#define MGT 256
#define NPROP 8192
#define NUM_CLASSES 80
#define IGNORED_CLASS 80
#define NUM_FG 128
#define NUM_BG 384
#define SENT 0xFFFFFFFFu
#define BS 1024
#define PPB 512                               // proposals per block (split-M x2)
#define NUM_MATCH_BLOCKS (BATCH * (NPROP / PPB))  // 256
#define KPT 8                                 // sample keys per thread
#define SELCAP 512                            // compaction capacity (>= ksel + bin)

typedef unsigned long long u64;

// d_out FLOAT32 layout (confirmed): matched_vals[16,8192] | matched_idxs[16,8192]
//   | sampled_idxs[16,512] | sampled_classes[16,512] | sampled_gt[16,512]
// ws: packed[B*N] int32 (512 KiB).  packed = (midx<<16) | (cls+1), cls+1 in [1,81].

// ---------------- Kernel 1: max-IoU match (R9/R10-verified math) ------------
__global__ __launch_bounds__(BS) void match_kernel(
    const float* __restrict__ gt_boxes, const int* __restrict__ gt_classes,
    const float* __restrict__ prop_boxes,
    float* __restrict__ out, int* __restrict__ packed)
{
#pragma clang fp contract(off)
    __shared__ u64 skey[PPB];                 // 4 KB

    const int tid  = threadIdx.x;
    const int b    = blockIdx.x >> 4;         // 16 chunks/row
    const int n    = ((blockIdx.x & 15) << 9) | (tid & (PPB - 1));
    const int half = tid >> 9;                // wave-uniform

    const float4* gt4 = (const float4*)gt_boxes + (size_t)b * MGT;
    const float4 p = ((const float4*)prop_boxes)[(size_t)b * NPROP + n];
    const float ap = (p.z - p.x) * (p.w - p.y);

    float best = 0.0f;
    int   bidx = 0;
    const int m0 = half * 128;
#pragma unroll 4
    for (int mm = 0; mm < 128; ++mm) {
        const int m = m0 + mm;
        const float4 g = gt4[m];              // wave-uniform -> s_load
        float ag  = (g.z - g.x) * (g.w - g.y);  // np op order, no FMA
        float ltx = fmaxf(g.x, p.x);
        float lty = fmaxf(g.y, p.y);
        float rbx = fminf(g.z, p.z);
        float rby = fminf(g.w, p.w);
        float w = fmaxf(rbx - ltx, 0.0f);
        float h = fmaxf(rby - lty, 0.0f);
        float inter = w * h;
        float s   = ag + ap;                  // area_g + area_p
        float uni = s - inter;
        // conservative filter (R8/R9/R10-verified): no true candidate skipped
        float thr = (best * uni) * 0.9999996f;
        if (inter > thr) {
            float iou = (uni > 0.0f) ? (inter / uni) : 0.0f;
            if (iou > best) { best = iou; bidx = m; }   // strict > = first idx
        }
    }
    // combine halves: max u64 key = larger iou, tie -> smaller gt idx
    u64 key = ((u64)__float_as_uint(best) << 32) | (uint32_t)(255 - bidx);
    const int pl = tid & (PPB - 1);
    if (half) skey[pl] = key;
    __syncthreads();
    if (half == 0) {
        u64 o = skey[pl];
        if (o > key) key = o;
        float bestf = __uint_as_float((uint32_t)(key >> 32));
        int   bi    = 255 - (int)(key & 0xFFu);

        const bool matched = (bestf >= 0.5f);
        int c = gt_classes[b * MGT + bi];
        if (c == IGNORED_CLASS) c = -1;
        if (!matched) c = NUM_CLASSES;

        const size_t on = (size_t)b * NPROP + n;
        out[on]                         = bestf;
        out[(size_t)BATCH * NPROP + on] = (float)bi;
        packed[on] = (bi << 16) | (c + 1);
    }
}

// ---------------- scan helpers (1024 threads = 16 waves; R9-verified) -------
__device__ __forceinline__ uint32_t wave_incl_scan_u32(uint32_t x) {
#pragma unroll
    for (int d = 1; d < 64; d <<= 1) {
        uint32_t y = __shfl_up(x, d, 64);
        if ((threadIdx.x & 63) >= d) x += y;
    }
    return x;
}

__device__ uint32_t block_excl_scan(uint32_t s, uint32_t* wsums) {
    const int tid = threadIdx.x, lane = tid & 63, wid = tid >> 6;
    __syncthreads();                 // protect wsums reuse across calls
    uint32_t incl = wave_incl_scan_u32(s);
    if (lane == 63) wsums[wid] = incl;
    __syncthreads();
    if (wid == 0) {
        uint32_t w  = (lane < 16) ? wsums[lane] : 0u;
        uint32_t wi = wave_incl_scan_u32(w);
        if (lane < 16) wsums[lane] = wi - w;
    }
    __syncthreads();
    return wsums[wid] + (incl - s);
}

// inclusive-scan hist[4096] in place; find bin with incl >= kk > prev.
__device__ void scan_and_find(uint32_t* hist, uint32_t* wsums, uint32_t kk,
                              uint32_t* sc_b, uint32_t* sc_p) {
    const int tid = threadIdx.x;
    __syncthreads();                 // histogram atomics complete
    const int base = tid * 4;
    uint32_t v0 = hist[base], v1 = hist[base+1], v2 = hist[base+2], v3 = hist[base+3];
    uint32_t pre = block_excl_scan(v0+v1+v2+v3, wsums);
    uint32_t i0 = pre+v0, i1 = i0+v1, i2 = i1+v2, i3 = i2+v3;
    hist[base] = i0; hist[base+1] = i1; hist[base+2] = i2; hist[base+3] = i3;
    __syncthreads();
    uint32_t prev = (base == 0) ? 0u : hist[base-1];
    uint32_t inc[4] = {i0, i1, i2, i3};
#pragma unroll
    for (int j = 0; j < 4; ++j) {
        if (inc[j] >= kk && prev < kk) { *sc_b = (uint32_t)(base+j); *sc_p = prev; }
        prev = inc[j];
    }
    __syncthreads();
}

// ---------------- Kernel 2: 2-level radix cut + compact + rank scatter ------
// One block per (row, pass), 32 blocks in parallel. After L2 the cut is a
// 24-bit prefix; compacting all keys with prefix <= cut gives a superset of
// the top-ksel of size <= ksel + (24-bit-bin count ~ 1-3). Exact (key,idx)
// u64 rank-scatter then reproduces lax.top_k exactly (pri desc, idx asc).
__global__ __launch_bounds__(BS) void sample_kernel(
    const float* __restrict__ pri_f, const int* __restrict__ packed,
    float* __restrict__ out)
{
    __shared__ uint32_t hist[4096];   // 16 KB
    __shared__ uint32_t wsums[16];
    __shared__ uint32_t sc[8];        // b1,p1,b2,p2,-,-,C,selcount
    __shared__ u64      sel[SELCAP];  // 4 KB

    const int tid  = threadIdx.x;
    const int b    = blockIdx.x >> 1;
    const int pass = blockIdx.x & 1;
    const int K    = pass ? NUM_BG : NUM_FG;
    const int off  = pass ? NUM_FG : 0;

    const int* pk = packed + (size_t)b * NPROP;

    float* s_idx = out + (size_t)2 * BATCH * NPROP + (size_t)b * 512;
    float* s_cls = s_idx + (size_t)BATCH * 512;
    float* s_gt  = s_idx + (size_t)2 * BATCH * 512;

    if (tid < 8) sc[tid] = 0u;
    for (int i = tid; i < 4096; i += BS) hist[i] = 0u;
    __syncthreads();

    // build keys (vector loads); cbase = tid*8 -> ascending-index ownership
    uint32_t key[KPT];
    const int cbase = tid * KPT;
    uint32_t creal = 0;
    {
        const int4*   pk4 = (const int4*)(pk) + tid * 2;
        const float4* pr4 = (const float4*)(pri_f + (size_t)b * NPROP) + tid * 2;
        int   pv[KPT];
        float pr[KPT];
        int4 a0 = pk4[0], a1 = pk4[1];
        float4 r0 = pr4[0], r1 = pr4[1];
        pv[0]=a0.x; pv[1]=a0.y; pv[2]=a0.z; pv[3]=a0.w;
        pv[4]=a1.x; pv[5]=a1.y; pv[6]=a1.z; pv[7]=a1.w;
        pr[0]=r0.x; pr[1]=r0.y; pr[2]=r0.z; pr[3]=r0.w;
        pr[4]=r1.x; pr[5]=r1.y; pr[6]=r1.z; pr[7]=r1.w;
#pragma unroll
        for (int j = 0; j < KPT; ++j) {
            const int c = (pv[j] & 0xFFFF) - 1;
            const bool m = pass ? (c == NUM_CLASSES) : (c >= 0 && c != NUM_CLASSES);
            uint32_t bits = __float_as_uint(pr[j]);
            uint32_t ord  = (bits & 0x80000000u) ? ~bits : (bits | 0x80000000u);
            key[j] = m ? ~ord : SENT;            // real keys < 0x80000000
            u64 bal = __ballot(m);
            if ((tid & 63) == 0) creal += __popcll(bal);
        }
    }
    if ((tid & 63) == 0 && creal) atomicAdd(&sc[6], creal);
    __syncthreads();
    const uint32_t C    = sc[6];
    const uint32_t ksel = (C < (uint32_t)K) ? C : (uint32_t)K;

    if (C > 0) {
        uint32_t top24cut;
        if (C <= (uint32_t)K) {
            top24cut = 0x7FFFFFu;                // all real keys (prefix <= this)
        } else {
            // L1: bits [31:20]
#pragma unroll
            for (int j = 0; j < KPT; ++j)
                if (key[j] < 0x80000000u) atomicAdd(&hist[key[j] >> 20], 1u);
            scan_and_find(hist, wsums, ksel, &sc[0], &sc[1]);
            const uint32_t b1 = sc[0], p1 = sc[1];
            const uint32_t k2 = ksel - p1;
            for (int i = tid; i < 4096; i += BS) hist[i] = 0u;
            __syncthreads();

            // L2: bits [19:8] within b1 -> 24-bit cut prefix
#pragma unroll
            for (int j = 0; j < KPT; ++j)
                if ((key[j] >> 20) == b1) atomicAdd(&hist[(key[j] >> 8) & 0xFFFu], 1u);
            scan_and_find(hist, wsums, k2, &sc[2], &sc[3]);
            top24cut = (b1 << 12) | sc[2];
        }

        // compact every key with prefix <= cut (superset of top-ksel, <= SELCAP)
#pragma unroll
        for (int j = 0; j < KPT; ++j) {
            if ((key[j] >> 8) <= top24cut) {     // SENT>>8 = 0xFFFFFF never passes
                uint32_t pos = atomicAdd(&sc[7], 1u);
                if (pos < SELCAP) sel[pos] = ((u64)key[j] << 32) | (uint32_t)(cbase + j);
            }
        }
        __syncthreads();
        uint32_t Scnt = sc[7]; if (Scnt > SELCAP) Scnt = SELCAP;

        // rank scatter: rank = #(u64 keys < mine); write ranks < ksel only
        for (uint32_t j = tid; j < Scnt; j += BS) {
            const u64 kj = sel[j];
            uint32_t r = 0;
            for (uint32_t i = 0; i < Scnt; ++i) r += (sel[i] < kj);
            if (r < ksel) {
                const uint32_t idx = (uint32_t)kj;
                const int pv = pk[idx];
                s_idx[off + r] = (float)idx;
                s_cls[off + r] = (float)((pv & 0xFFFF) - 1);
                s_gt[off + r]  = (float)(pv >> 16);
            }
        }
    }

    // filler: first (K - ksel) masked-out indices ascending (invalid slots)
    if (ksel < (uint32_t)K) {
        const uint32_t F = (uint32_t)K - ksel;
        uint32_t sv = 0;
#pragma unroll
        for (int j = 0; j < KPT; ++j) sv += (key[j] == SENT);
        uint32_t run = block_excl_scan(sv, wsums);
#pragma unroll
        for (int j = 0; j < KPT; ++j) {
            if (key[j] == SENT) {
                if (run < F) {
                    const int slot = off + (int)ksel + (int)run;
                    s_idx[slot] = (float)(cbase + j);
                    s_cls[slot] = -1.0f;
                    s_gt[slot]  = -1.0f;
                }
                ++run;
            }
        }
    }
}

extern "C" void kernel_launch(void* const* d_in, const int* in_sizes, int n_in,
                              void* d_out, int out_size, void* d_ws, size_t ws_size,
                              hipStream_t stream) {
    const float* gt_boxes   = (const float*)d_in[0];
    const int*   gt_classes = (const int*)d_in[1];
    const float* prop_boxes = (const float*)d_in[2];
    const float* rand_pri   = (const float*)d_in[3];
    float* out  = (float*)d_out;
    int* packed = (int*)d_ws;                    // [B*N] = 512 KiB

    match_kernel<<<NUM_MATCH_BLOCKS, BS, 0, stream>>>(
        gt_boxes, gt_classes, prop_boxes, out, packed);
    sample_kernel<<<BATCH * 2, BS, 0, stream>>>(rand_pri, packed, out);
}

// Round 12
// 102.302 us; speedup vs baseline: 2.1498x; 1.0305x over previous
//
#include <hip/hip_runtime.h>
#include <stdint.h>

// Problem constants
#define BATCH 16
#define MGT 256
#define NPROP 8192
#define NUM_CLASSES 80
#define IGNORED_CLASS 80
#define NUM_FG 128
#define NUM_BG 384
#define SENT 0xFFFFFFFFu
#define BS 1024
#define PPB 256                               // proposals per block (split-M x4)
#define NUM_MATCH_BLOCKS (BATCH * (NPROP / PPB))  // 512 -> 2 blocks/CU
#define KPT 8                                 // sample keys per thread
#define SELCAP 512                            // compaction capacity

typedef unsigned long long u64;

// d_out FLOAT32 layout (confirmed): matched_vals[16,8192] | matched_idxs[16,8192]
//   | sampled_idxs[16,512] | sampled_classes[16,512] | sampled_gt[16,512]
// ws: packed[B*N] int32 (512 KiB).  packed = (midx<<16) | (cls+1), cls+1 in [1,81].

// ---------------- Kernel 1: max-IoU match, split-M x4 ----------------
// 512 blocks x 1024 threads; thread (pl, q) scans gt [q*64, q*64+64) for
// proposal pl; u64-key combine (iou_bits<<32 | (255-bidx)): max = larger iou,
// tie -> smaller gt idx (R5..R11-verified).
__global__ __launch_bounds__(BS) void match_kernel(
    const float* __restrict__ gt_boxes, const int* __restrict__ gt_classes,
    const float* __restrict__ prop_boxes,
    float* __restrict__ out, int* __restrict__ packed)
{
#pragma clang fp contract(off)
    __shared__ u64 skey[3 * PPB];             // 6 KB

    const int tid = threadIdx.x;
    const int pl  = tid & (PPB - 1);
    const int q   = tid >> 8;                 // wave-uniform (4 waves per quarter)
    const int b   = blockIdx.x >> 5;          // 32 chunks/row
    const int n   = ((blockIdx.x & 31) << 8) | pl;

    const float4* gt4 = (const float4*)gt_boxes + (size_t)b * MGT;
    const float4 p = ((const float4*)prop_boxes)[(size_t)b * NPROP + n];
    const float ap = (p.z - p.x) * (p.w - p.y);

    float best = 0.0f;
    int   bidx = 0;
    const int m0 = q * 64;
#pragma unroll 8
    for (int mm = 0; mm < 64; ++mm) {
        const int m = m0 + mm;
        const float4 g = gt4[m];              // wave-uniform -> s_load_dwordx4
        float ag  = (g.z - g.x) * (g.w - g.y);  // np op order, no FMA
        float ltx = fmaxf(g.x, p.x);
        float lty = fmaxf(g.y, p.y);
        float rbx = fminf(g.z, p.z);
        float rby = fminf(g.w, p.w);
        float w = fmaxf(rbx - ltx, 0.0f);
        float h = fmaxf(rby - lty, 0.0f);
        float inter = w * h;
        float s   = ag + ap;                  // area_g + area_p
        float uni = s - inter;
        // conservative filter (R8..R11-verified): iou > best needs
        // inter > best*uni (real); thr < best*uni exactly -> none skipped.
        float thr = (best * uni) * 0.9999996f;
        if (inter > thr) {
            float iou = (uni > 0.0f) ? (inter / uni) : 0.0f;
            if (iou > best) { best = iou; bidx = m; }   // strict > = first idx
        }
    }
    u64 key = ((u64)__float_as_uint(best) << 32) | (uint32_t)(255 - bidx);
    if (q) skey[(q - 1) * PPB + pl] = key;
    __syncthreads();
    if (q == 0) {
        u64 o0 = skey[pl];
        u64 o1 = skey[PPB + pl];
        u64 o2 = skey[2 * PPB + pl];
        if (o0 > key) key = o0;
        if (o1 > key) key = o1;
        if (o2 > key) key = o2;
        float bestf = __uint_as_float((uint32_t)(key >> 32));
        int   bi    = 255 - (int)(key & 0xFFu);

        const bool matched = (bestf >= 0.5f);
        int c = gt_classes[b * MGT + bi];
        if (c == IGNORED_CLASS) c = -1;
        if (!matched) c = NUM_CLASSES;

        const size_t on = (size_t)b * NPROP + n;
        out[on]                         = bestf;
        out[(size_t)BATCH * NPROP + on] = (float)bi;
        packed[on] = (bi << 16) | (c + 1);
    }
}

// ---------------- scan helpers (1024 threads = 16 waves; R9-verified) -------
__device__ __forceinline__ uint32_t wave_incl_scan_u32(uint32_t x) {
#pragma unroll
    for (int d = 1; d < 64; d <<= 1) {
        uint32_t y = __shfl_up(x, d, 64);
        if ((threadIdx.x & 63) >= d) x += y;
    }
    return x;
}

__device__ uint32_t block_excl_scan(uint32_t s, uint32_t* wsums) {
    const int tid = threadIdx.x, lane = tid & 63, wid = tid >> 6;
    __syncthreads();                 // protect wsums reuse across calls
    uint32_t incl = wave_incl_scan_u32(s);
    if (lane == 63) wsums[wid] = incl;
    __syncthreads();
    if (wid == 0) {
        uint32_t w  = (lane < 16) ? wsums[lane] : 0u;
        uint32_t wi = wave_incl_scan_u32(w);
        if (lane < 16) wsums[lane] = wi - w;
    }
    __syncthreads();
    return wsums[wid] + (incl - s);
}

// inclusive-scan hist[4096] in place; find bin with incl >= kk > prev.
__device__ void scan_and_find(uint32_t* hist, uint32_t* wsums, uint32_t kk,
                              uint32_t* sc_b, uint32_t* sc_p) {
    const int tid = threadIdx.x;
    __syncthreads();                 // histogram atomics complete
    const int base = tid * 4;
    uint32_t v0 = hist[base], v1 = hist[base+1], v2 = hist[base+2], v3 = hist[base+3];
    uint32_t pre = block_excl_scan(v0+v1+v2+v3, wsums);
    uint32_t i0 = pre+v0, i1 = i0+v1, i2 = i1+v2, i3 = i2+v3;
    hist[base] = i0; hist[base+1] = i1; hist[base+2] = i2; hist[base+3] = i3;
    __syncthreads();
    uint32_t prev = (base == 0) ? 0u : hist[base-1];
    uint32_t inc[4] = {i0, i1, i2, i3};
#pragma unroll
    for (int j = 0; j < 4; ++j) {
        if (inc[j] >= kk && prev < kk) { *sc_b = (uint32_t)(base+j); *sc_p = prev; }
        prev = inc[j];
    }
    __syncthreads();
}

// ---------------- Kernel 2: 2-level radix cut + compact + rank scatter ------
// (byte-identical to R11 — passed with absmax 0.0)
__global__ __launch_bounds__(BS) void sample_kernel(
    const float* __restrict__ pri_f, const int* __restrict__ packed,
    float* __restrict__ out)
{
    __shared__ uint32_t hist[4096];   // 16 KB
    __shared__ uint32_t wsums[16];
    __shared__ uint32_t sc[8];        // b1,p1,b2,p2,-,-,C,selcount
    __shared__ u64      sel[SELCAP];  // 4 KB

    const int tid  = threadIdx.x;
    const int b    = blockIdx.x >> 1;
    const int pass = blockIdx.x & 1;
    const int K    = pass ? NUM_BG : NUM_FG;
    const int off  = pass ? NUM_FG : 0;

    const int* pk = packed + (size_t)b * NPROP;

    float* s_idx = out + (size_t)2 * BATCH * NPROP + (size_t)b * 512;
    float* s_cls = s_idx + (size_t)BATCH * 512;
    float* s_gt  = s_idx + (size_t)2 * BATCH * 512;

    if (tid < 8) sc[tid] = 0u;
    for (int i = tid; i < 4096; i += BS) hist[i] = 0u;
    __syncthreads();

    // build keys (vector loads); cbase = tid*8 -> ascending-index ownership
    uint32_t key[KPT];
    const int cbase = tid * KPT;
    uint32_t creal = 0;
    {
        const int4*   pk4 = (const int4*)(pk) + tid * 2;
        const float4* pr4 = (const float4*)(pri_f + (size_t)b * NPROP) + tid * 2;
        int   pv[KPT];
        float pr[KPT];
        int4 a0 = pk4[0], a1 = pk4[1];
        float4 r0 = pr4[0], r1 = pr4[1];
        pv[0]=a0.x; pv[1]=a0.y; pv[2]=a0.z; pv[3]=a0.w;
        pv[4]=a1.x; pv[5]=a1.y; pv[6]=a1.z; pv[7]=a1.w;
        pr[0]=r0.x; pr[1]=r0.y; pr[2]=r0.z; pr[3]=r0.w;
        pr[4]=r1.x; pr[5]=r1.y; pr[6]=r1.z; pr[7]=r1.w;
#pragma unroll
        for (int j = 0; j < KPT; ++j) {
            const int c = (pv[j] & 0xFFFF) - 1;
            const bool m = pass ? (c == NUM_CLASSES) : (c >= 0 && c != NUM_CLASSES);
            uint32_t bits = __float_as_uint(pr[j]);
            uint32_t ord  = (bits & 0x80000000u) ? ~bits : (bits | 0x80000000u);
            key[j] = m ? ~ord : SENT;            // real keys < 0x80000000
            u64 bal = __ballot(m);
            if ((tid & 63) == 0) creal += __popcll(bal);
        }
    }
    if ((tid & 63) == 0 && creal) atomicAdd(&sc[6], creal);
    __syncthreads();
    const uint32_t C    = sc[6];
    const uint32_t ksel = (C < (uint32_t)K) ? C : (uint32_t)K;

    if (C > 0) {
        uint32_t top24cut;
        if (C <= (uint32_t)K) {
            top24cut = 0x7FFFFFu;                // all real keys (prefix <= this)
        } else {
            // L1: bits [31:20]
#pragma unroll
            for (int j = 0; j < KPT; ++j)
                if (key[j] < 0x80000000u) atomicAdd(&hist[key[j] >> 20], 1u);
            scan_and_find(hist, wsums, ksel, &sc[0], &sc[1]);
            const uint32_t b1 = sc[0], p1 = sc[1];
            const uint32_t k2 = ksel - p1;
            for (int i = tid; i < 4096; i += BS) hist[i] = 0u;
            __syncthreads();

            // L2: bits [19:8] within b1 -> 24-bit cut prefix
#pragma unroll
            for (int j = 0; j < KPT; ++j)
                if ((key[j] >> 20) == b1) atomicAdd(&hist[(key[j] >> 8) & 0xFFFu], 1u);
            scan_and_find(hist, wsums, k2, &sc[2], &sc[3]);
            top24cut = (b1 << 12) | sc[2];
        }

        // compact every key with prefix <= cut (superset of top-ksel)
#pragma unroll
        for (int j = 0; j < KPT; ++j) {
            if ((key[j] >> 8) <= top24cut) {     // SENT>>8 never passes
                uint32_t pos = atomicAdd(&sc[7], 1u);
                if (pos < SELCAP) sel[pos] = ((u64)key[j] << 32) | (uint32_t)(cbase + j);
            }
        }
        __syncthreads();
        uint32_t Scnt = sc[7]; if (Scnt > SELCAP) Scnt = SELCAP;

        // rank scatter: rank = #(u64 keys < mine); write ranks < ksel only
        for (uint32_t j = tid; j < Scnt; j += BS) {
            const u64 kj = sel[j];
            uint32_t r = 0;
            for (uint32_t i = 0; i < Scnt; ++i) r += (sel[i] < kj);
            if (r < ksel) {
                const uint32_t idx = (uint32_t)kj;
                const int pv = pk[idx];
                s_idx[off + r] = (float)idx;
                s_cls[off + r] = (float)((pv & 0xFFFF) - 1);
                s_gt[off + r]  = (float)(pv >> 16);
            }
        }
    }

    // filler: first (K - ksel) masked-out indices ascending (invalid slots)
    if (ksel < (uint32_t)K) {
        const uint32_t F = (uint32_t)K - ksel;
        uint32_t sv = 0;
#pragma unroll
        for (int j = 0; j < KPT; ++j) sv += (key[j] == SENT);
        uint32_t run = block_excl_scan(sv, wsums);
#pragma unroll
        for (int j = 0; j < KPT; ++j) {
            if (key[j] == SENT) {
                if (run < F) {
                    const int slot = off + (int)ksel + (int)run;
                    s_idx[slot] = (float)(cbase + j);
                    s_cls[slot] = -1.0f;
                    s_gt[slot]  = -1.0f;
                }
                ++run;
            }
        }
    }
}

extern "C" void kernel_launch(void* const* d_in, const int* in_sizes, int n_in,
                              void* d_out, int out_size, void* d_ws, size_t ws_size,
                              hipStream_t stream) {
    const float* gt_boxes   = (const float*)d_in[0];
    const int*   gt_classes = (const int*)d_in[1];
    const float* prop_boxes = (const float*)d_in[2];
    const float* rand_pri   = (const float*)d_in[3];
    float* out  = (float*)d_out;
    int* packed = (int*)d_ws;                    // [B*N] = 512 KiB

    match_kernel<<<NUM_MATCH_BLOCKS, BS, 0, stream>>>(
        gt_boxes, gt_classes, prop_boxes, out, packed);
    sample_kernel<<<BATCH * 2, BS, 0, stream>>>(rand_pri, packed, out);
}

// Round 13
// 96.649 us; speedup vs baseline: 2.2756x; 1.0585x over previous
//
#include <hip/hip_runtime.h>
#include <stdint.h>

// Problem constants
#define BATCH 16
#define MGT 256
#define NPROP 8192
#define NUM_CLASSES 80
#define IGNORED_CLASS 80
#define NUM_FG 128
#define NUM_BG 384
#define SENT 0xFFFFFFFFu
#define BS 1024
#define PPB 256                               // proposals per block (split-M x4)
#define NUM_MATCH_BLOCKS (BATCH * (NPROP / PPB))  // 512 -> 2 blocks/CU
#define KPT 8                                 // sample keys per thread
#define SELCAP 512                            // compaction capacity

typedef unsigned long long u64;

// d_out FLOAT32 layout (confirmed): matched_vals[16,8192] | matched_idxs[16,8192]
//   | sampled_idxs[16,512] | sampled_classes[16,512] | sampled_gt[16,512]
// ws: packed[B*N] int32 (512 KiB).  packed = (midx<<16) | (cls+1), cls+1 in [1,81].

// ---------------- Kernel 1: max-IoU match, split-M x4, LDS gt tile ----------
// 512 blocks x 1024 threads; thread (pl, q) scans gt [q*64, q*64+64) for
// proposal pl; u64-key combine (iou_bits<<32 | (255-bidx)): max = larger iou,
// tie -> smaller gt idx (R5..R12-verified).
__global__ __launch_bounds__(BS) void match_kernel(
    const float* __restrict__ gt_boxes, const int* __restrict__ gt_classes,
    const float* __restrict__ prop_boxes,
    float* __restrict__ out, int* __restrict__ packed)
{
#pragma clang fp contract(off)
    __shared__ float4 sbox[MGT];              // 4 KB gt boxes
    __shared__ float  sga[MGT];               // 1 KB gt areas
    __shared__ u64    skey[3 * PPB];          // 6 KB

    const int tid = threadIdx.x;
    const int pl  = tid & (PPB - 1);
    const int q   = tid >> 8;                 // wave-uniform
    const int b   = blockIdx.x >> 5;          // 32 chunks/row
    const int n   = ((blockIdx.x & 31) << 8) | pl;

    // stage gt tile: 256 of the 1024 threads load one box each
    if (tid < MGT) {
        const float4 g = ((const float4*)gt_boxes)[(size_t)b * MGT + tid];
        sbox[tid] = g;
        sga[tid]  = (g.z - g.x) * (g.w - g.y);   // np op order, no FMA
    }
    __syncthreads();

    const float4 p = ((const float4*)prop_boxes)[(size_t)b * NPROP + n];
    const float ap = (p.z - p.x) * (p.w - p.y);

    float best = 0.0f;
    int   bidx = 0;
    const int m0 = q * 64;
#pragma unroll 8
    for (int mm = 0; mm < 64; ++mm) {
        const int m = m0 + mm;
        const float4 g = sbox[m];             // LDS broadcast (wave-uniform m)
        const float ag = sga[m];
        float ltx = fmaxf(g.x, p.x);
        float lty = fmaxf(g.y, p.y);
        float rbx = fminf(g.z, p.z);
        float rby = fminf(g.w, p.w);
        float w = fmaxf(rbx - ltx, 0.0f);
        float h = fmaxf(rby - lty, 0.0f);
        float inter = w * h;
        float s   = ag + ap;                  // area_g + area_p
        float uni = s - inter;
        // conservative filter (R8..R12-verified): iou > best needs
        // inter > best*uni (real); thr < best*uni exactly -> none skipped.
        float thr = (best * uni) * 0.9999996f;
        if (inter > thr) {
            float iou = (uni > 0.0f) ? (inter / uni) : 0.0f;
            if (iou > best) { best = iou; bidx = m; }   // strict > = first idx
        }
    }
    u64 key = ((u64)__float_as_uint(best) << 32) | (uint32_t)(255 - bidx);
    if (q) skey[(q - 1) * PPB + pl] = key;
    __syncthreads();
    if (q == 0) {
        u64 o0 = skey[pl];
        u64 o1 = skey[PPB + pl];
        u64 o2 = skey[2 * PPB + pl];
        if (o0 > key) key = o0;
        if (o1 > key) key = o1;
        if (o2 > key) key = o2;
        float bestf = __uint_as_float((uint32_t)(key >> 32));
        int   bi    = 255 - (int)(key & 0xFFu);

        const bool matched = (bestf >= 0.5f);
        int c = gt_classes[b * MGT + bi];
        if (c == IGNORED_CLASS) c = -1;
        if (!matched) c = NUM_CLASSES;

        const size_t on = (size_t)b * NPROP + n;
        out[on]                         = bestf;
        out[(size_t)BATCH * NPROP + on] = (float)bi;
        packed[on] = (bi << 16) | (c + 1);
    }
}

// ---------------- scan helpers (1024 threads = 16 waves; R9-verified) -------
__device__ __forceinline__ uint32_t wave_incl_scan_u32(uint32_t x) {
#pragma unroll
    for (int d = 1; d < 64; d <<= 1) {
        uint32_t y = __shfl_up(x, d, 64);
        if ((threadIdx.x & 63) >= d) x += y;
    }
    return x;
}

__device__ uint32_t block_excl_scan(uint32_t s, uint32_t* wsums) {
    const int tid = threadIdx.x, lane = tid & 63, wid = tid >> 6;
    __syncthreads();                 // protect wsums reuse across calls
    uint32_t incl = wave_incl_scan_u32(s);
    if (lane == 63) wsums[wid] = incl;
    __syncthreads();
    if (wid == 0) {
        uint32_t w  = (lane < 16) ? wsums[lane] : 0u;
        uint32_t wi = wave_incl_scan_u32(w);
        if (lane < 16) wsums[lane] = wi - w;
    }
    __syncthreads();
    return wsums[wid] + (incl - s);
}

// inclusive-scan hist[4096] in place; find bin with incl >= kk > prev.
__device__ void scan_and_find(uint32_t* hist, uint32_t* wsums, uint32_t kk,
                              uint32_t* sc_b, uint32_t* sc_p) {
    const int tid = threadIdx.x;
    __syncthreads();                 // histogram atomics complete
    const int base = tid * 4;
    uint32_t v0 = hist[base], v1 = hist[base+1], v2 = hist[base+2], v3 = hist[base+3];
    uint32_t pre = block_excl_scan(v0+v1+v2+v3, wsums);
    uint32_t i0 = pre+v0, i1 = i0+v1, i2 = i1+v2, i3 = i2+v3;
    hist[base] = i0; hist[base+1] = i1; hist[base+2] = i2; hist[base+3] = i3;
    __syncthreads();
    uint32_t prev = (base == 0) ? 0u : hist[base-1];
    uint32_t inc[4] = {i0, i1, i2, i3};
#pragma unroll
    for (int j = 0; j < 4; ++j) {
        if (inc[j] >= kk && prev < kk) { *sc_b = (uint32_t)(base+j); *sc_p = prev; }
        prev = inc[j];
    }
    __syncthreads();
}

// ---------------- Kernel 2: 2-level radix cut + compact + rank scatter ------
// (byte-identical to R11/R12 — passed twice with absmax 0.0)
__global__ __launch_bounds__(BS) void sample_kernel(
    const float* __restrict__ pri_f, const int* __restrict__ packed,
    float* __restrict__ out)
{
    __shared__ uint32_t hist[4096];   // 16 KB
    __shared__ uint32_t wsums[16];
    __shared__ uint32_t sc[8];        // b1,p1,b2,p2,-,-,C,selcount
    __shared__ u64      sel[SELCAP];  // 4 KB

    const int tid  = threadIdx.x;
    const int b    = blockIdx.x >> 1;
    const int pass = blockIdx.x & 1;
    const int K    = pass ? NUM_BG : NUM_FG;
    const int off  = pass ? NUM_FG : 0;

    const int* pk = packed + (size_t)b * NPROP;

    float* s_idx = out + (size_t)2 * BATCH * NPROP + (size_t)b * 512;
    float* s_cls = s_idx + (size_t)BATCH * 512;
    float* s_gt  = s_idx + (size_t)2 * BATCH * 512;

    if (tid < 8) sc[tid] = 0u;
    for (int i = tid; i < 4096; i += BS) hist[i] = 0u;
    __syncthreads();

    // build keys (vector loads); cbase = tid*8 -> ascending-index ownership
    uint32_t key[KPT];
    const int cbase = tid * KPT;
    uint32_t creal = 0;
    {
        const int4*   pk4 = (const int4*)(pk) + tid * 2;
        const float4* pr4 = (const float4*)(pri_f + (size_t)b * NPROP) + tid * 2;
        int   pv[KPT];
        float pr[KPT];
        int4 a0 = pk4[0], a1 = pk4[1];
        float4 r0 = pr4[0], r1 = pr4[1];
        pv[0]=a0.x; pv[1]=a0.y; pv[2]=a0.z; pv[3]=a0.w;
        pv[4]=a1.x; pv[5]=a1.y; pv[6]=a1.z; pv[7]=a1.w;
        pr[0]=r0.x; pr[1]=r0.y; pr[2]=r0.z; pr[3]=r0.w;
        pr[4]=r1.x; pr[5]=r1.y; pr[6]=r1.z; pr[7]=r1.w;
#pragma unroll
        for (int j = 0; j < KPT; ++j) {
            const int c = (pv[j] & 0xFFFF) - 1;
            const bool m = pass ? (c == NUM_CLASSES) : (c >= 0 && c != NUM_CLASSES);
            uint32_t bits = __float_as_uint(pr[j]);
            uint32_t ord  = (bits & 0x80000000u) ? ~bits : (bits | 0x80000000u);
            key[j] = m ? ~ord : SENT;            // real keys < 0x80000000
            u64 bal = __ballot(m);
            if ((tid & 63) == 0) creal += __popcll(bal);
        }
    }
    if ((tid & 63) == 0 && creal) atomicAdd(&sc[6], creal);
    __syncthreads();
    const uint32_t C    = sc[6];
    const uint32_t ksel = (C < (uint32_t)K) ? C : (uint32_t)K;

    if (C > 0) {
        uint32_t top24cut;
        if (C <= (uint32_t)K) {
            top24cut = 0x7FFFFFu;                // all real keys (prefix <= this)
        } else {
            // L1: bits [31:20]
#pragma unroll
            for (int j = 0; j < KPT; ++j)
                if (key[j] < 0x80000000u) atomicAdd(&hist[key[j] >> 20], 1u);
            scan_and_find(hist, wsums, ksel, &sc[0], &sc[1]);
            const uint32_t b1 = sc[0], p1 = sc[1];
            const uint32_t k2 = ksel - p1;
            for (int i = tid; i < 4096; i += BS) hist[i] = 0u;
            __syncthreads();

            // L2: bits [19:8] within b1 -> 24-bit cut prefix
#pragma unroll
            for (int j = 0; j < KPT; ++j)
                if ((key[j] >> 20) == b1) atomicAdd(&hist[(key[j] >> 8) & 0xFFFu], 1u);
            scan_and_find(hist, wsums, k2, &sc[2], &sc[3]);
            top24cut = (b1 << 12) | sc[2];
        }

        // compact every key with prefix <= cut (superset of top-ksel)
#pragma unroll
        for (int j = 0; j < KPT; ++j) {
            if ((key[j] >> 8) <= top24cut) {     // SENT>>8 never passes
                uint32_t pos = atomicAdd(&sc[7], 1u);
                if (pos < SELCAP) sel[pos] = ((u64)key[j] << 32) | (uint32_t)(cbase + j);
            }
        }
        __syncthreads();
        uint32_t Scnt = sc[7]; if (Scnt > SELCAP) Scnt = SELCAP;

        // rank scatter: rank = #(u64 keys < mine); write ranks < ksel only
        for (uint32_t j = tid; j < Scnt; j += BS) {
            const u64 kj = sel[j];
            uint32_t r = 0;
            for (uint32_t i = 0; i < Scnt; ++i) r += (sel[i] < kj);
            if (r < ksel) {
                const uint32_t idx = (uint32_t)kj;
                const int pv = pk[idx];
                s_idx[off + r] = (float)idx;
                s_cls[off + r] = (float)((pv & 0xFFFF) - 1);
                s_gt[off + r]  = (float)(pv >> 16);
            }
        }
    }

    // filler: first (K - ksel) masked-out indices ascending (invalid slots)
    if (ksel < (uint32_t)K) {
        const uint32_t F = (uint32_t)K - ksel;
        uint32_t sv = 0;
#pragma unroll
        for (int j = 0; j < KPT; ++j) sv += (key[j] == SENT);
        uint32_t run = block_excl_scan(sv, wsums);
#pragma unroll
        for (int j = 0; j < KPT; ++j) {
            if (key[j] == SENT) {
                if (run < F) {
                    const int slot = off + (int)ksel + (int)run;
                    s_idx[slot] = (float)(cbase + j);
                    s_cls[slot] = -1.0f;
                    s_gt[slot]  = -1.0f;
                }
                ++run;
            }
        }
    }
}

extern "C" void kernel_launch(void* const* d_in, const int* in_sizes, int n_in,
                              void* d_out, int out_size, void* d_ws, size_t ws_size,
                              hipStream_t stream) {
    const float* gt_boxes   = (const float*)d_in[0];
    const int*   gt_classes = (const int*)d_in[1];
    const float* prop_boxes = (const float*)d_in[2];
    const float* rand_pri   = (const float*)d_in[3];
    float* out  = (float*)d_out;
    int* packed = (int*)d_ws;                    // [B*N] = 512 KiB

    match_kernel<<<NUM_MATCH_BLOCKS, BS, 0, stream>>>(
        gt_boxes, gt_classes, prop_boxes, out, packed);
    sample_kernel<<<BATCH * 2, BS, 0, stream>>>(rand_pri, packed, out);
}